// Round 1
// baseline (149.410 us; speedup 1.0000x reference)
//
#include <hip/hip_runtime.h>
#include <hip/hip_bf16.h>
#include <stdint.h>

typedef __attribute__((ext_vector_type(8))) short bf16x8;
typedef __attribute__((ext_vector_type(4))) float f32x4;
typedef __attribute__((ext_vector_type(4))) unsigned short us4;

#define MFMA(a, b, c) __builtin_amdgcn_mfma_f32_16x16x32_bf16(a, b, c, 0, 0, 0)

__device__ __forceinline__ short f2bf(float f) {
    union { float f; uint32_t u; } v; v.f = f;
    uint32_t u = v.u;
    u = (u + 0x7FFFu + ((u >> 16) & 1u)) >> 16;  // RNE
    return (short)u;
}

// ---------------------------------------------------------------------------
// Kernel 1: build WT_bf16[192][1024] (cols 0-63=Wq*0.125, 64-127=Wk, 128-191=Wv)
// and fused bias biasC[192] (bq*0.125 | bk | bv).
// ---------------------------------------------------------------------------
__global__ void wt_prep(const float* __restrict__ Wk, const float* __restrict__ bk,
                        const float* __restrict__ Wq, const float* __restrict__ bq,
                        const float* __restrict__ Wv, const float* __restrict__ bv,
                        short* __restrict__ WT, float* __restrict__ biasC) {
    int i = blockIdx.x * 256 + threadIdx.x;
    if (i < 192 * 1024) {
        int c = i >> 10, k = i & 1023, cc = c & 63;
        const float* W; float sc;
        if (c < 64)       { W = Wq; sc = 0.125f; }
        else if (c < 128) { W = Wk; sc = 1.0f;   }
        else              { W = Wv; sc = 1.0f;   }
        WT[i] = f2bf(W[k * 64 + cc] * sc);
    }
    if (blockIdx.x == 0 && threadIdx.x < 192) {
        int c = threadIdx.x;
        float bb;
        if (c < 64)       bb = bq[c] * 0.125f;
        else if (c < 128) bb = bk[c - 64];
        else              bb = bv[c - 128];
        biasC[c] = bb;
    }
}

// ---------------------------------------------------------------------------
// Kernel 2: QKV projection. C(16384x192) = X(16384x1024) @ WT^T, +bias.
// 256 blocks x 256 thr (4 waves). Wave w owns 16 rows; 12 col-tiles of 16.
// Writes Qb/Kb row-major bf16 [b][s][64], V transposed Vt [b][64][4096].
// ---------------------------------------------------------------------------
__global__ __launch_bounds__(256) void qkv_proj(
        const float* __restrict__ X, const short* __restrict__ WT,
        const float* __restrict__ biasC,
        short* __restrict__ Qb, short* __restrict__ Kb, short* __restrict__ Vt) {
    const int lane = threadIdx.x & 63, w = threadIdx.x >> 6;
    const int row0 = blockIdx.x * 64;
    const int arow = row0 + w * 16 + (lane & 15);
    const int koff = (lane >> 4) * 8;

    f32x4 acc[12];
#pragma unroll
    for (int t = 0; t < 12; t++) acc[t] = (f32x4){0.f, 0.f, 0.f, 0.f};

    const float* xbase = X + (size_t)arow * 1024 + koff;
    const short* wbase = WT + (size_t)(lane & 15) * 1024 + koff;

    for (int kc = 0; kc < 1024; kc += 32) {
        const float4 a0 = *(const float4*)(xbase + kc);
        const float4 a1 = *(const float4*)(xbase + kc + 4);
        bf16x8 af;
        af[0] = f2bf(a0.x); af[1] = f2bf(a0.y); af[2] = f2bf(a0.z); af[3] = f2bf(a0.w);
        af[4] = f2bf(a1.x); af[5] = f2bf(a1.y); af[6] = f2bf(a1.z); af[7] = f2bf(a1.w);
#pragma unroll
        for (int ct = 0; ct < 12; ct++) {
            bf16x8 bf = *(const bf16x8*)(wbase + (size_t)ct * 16 * 1024 + kc);
            acc[ct] = MFMA(af, bf, acc[ct]);
        }
    }

    const int rbase = row0 + w * 16 + (lane >> 4) * 4;  // first of 4 output rows
    const int b = rbase >> 12, s0 = rbase & 4095;
#pragma unroll
    for (int ct = 0; ct < 12; ct++) {
        const int col = ct * 16 + (lane & 15);
        const float bias = biasC[col];
        if (ct < 4) {            // Q
            short* dst = Qb + (size_t)rbase * 64 + col;
#pragma unroll
            for (int r = 0; r < 4; r++) dst[r * 64] = f2bf(acc[ct][r] + bias);
        } else if (ct < 8) {     // K
            short* dst = Kb + (size_t)rbase * 64 + (col - 64);
#pragma unroll
            for (int r = 0; r < 4; r++) dst[r * 64] = f2bf(acc[ct][r] + bias);
        } else {                 // V -> transposed, 4 consecutive s => 8B store
            const int hd = col - 128;
            us4 pk;
#pragma unroll
            for (int r = 0; r < 4; r++) pk[r] = (unsigned short)f2bf(acc[ct][r] + bias);
            *(us4*)(Vt + ((size_t)(b * 64 + hd)) * 4096 + s0) = pk;
        }
    }
}

// ---------------------------------------------------------------------------
// Kernel 3: causal flash attention. Block = 16 q-rows of one batch; 4 waves
// split the KV tiles (wave w: tiles w, w+4, ...), merged at the end.
// ---------------------------------------------------------------------------
__global__ __launch_bounds__(256) void attn(
        const short* __restrict__ Qb, const short* __restrict__ Kb,
        const short* __restrict__ Vt, float* __restrict__ out) {
    const int lane = threadIdx.x & 63, w = threadIdx.x >> 6;
    const int bid = blockIdx.x;
    const int b = bid >> 8, qt = bid & 255;
    const int row16 = qt * 16;
    const int lt = qt >> 2;                 // last (diagonal) KV tile index

    __shared__ short P_lds[4][16][64];
    __shared__ float c_m[4][16], c_l[4][16];
    __shared__ float c_o[4][16][64];

    const size_t bbase = (size_t)b * 4096 * 64;
    const int koff = (lane >> 4) * 8;

    const short* qp = Qb + bbase + (size_t)(row16 + (lane & 15)) * 64 + koff;
    const bf16x8 qf0 = *(const bf16x8*)(qp);
    const bf16x8 qf1 = *(const bf16x8*)(qp + 32);

    f32x4 o[4];
    float m[4], ls[4];
#pragma unroll
    for (int t = 0; t < 4; t++) { o[t] = (f32x4){0.f, 0.f, 0.f, 0.f}; m[t] = -__builtin_inff(); ls[t] = 0.f; }

    for (int kt = w; kt <= lt; kt += 4) {
        const short* kb = Kb + bbase + (size_t)kt * 64 * 64;
        f32x4 s[4];
#pragma unroll
        for (int c = 0; c < 4; c++) {
            const short* kp = kb + (size_t)(c * 16 + (lane & 15)) * 64 + koff;
            bf16x8 kf0 = *(const bf16x8*)(kp);
            bf16x8 kf1 = *(const bf16x8*)(kp + 32);
            f32x4 z = (f32x4){0.f, 0.f, 0.f, 0.f};
            z = MFMA(qf0, kf0, z);
            s[c] = MFMA(qf1, kf1, z);
        }
        if (kt == lt) {   // diagonal tile: mask key > q
#pragma unroll
            for (int c = 0; c < 4; c++) {
                const int key = kt * 64 + c * 16 + (lane & 15);
#pragma unroll
                for (int r = 0; r < 4; r++) {
                    const int q = row16 + (lane >> 4) * 4 + r;
                    if (key > q) s[c][r] = -1e30f;
                }
            }
        }
        float fac[4];
#pragma unroll
        for (int r = 0; r < 4; r++) {
            float v = fmaxf(fmaxf(s[0][r], s[1][r]), fmaxf(s[2][r], s[3][r]));
            v = fmaxf(v, __shfl_xor(v, 1));
            v = fmaxf(v, __shfl_xor(v, 2));
            v = fmaxf(v, __shfl_xor(v, 4));
            v = fmaxf(v, __shfl_xor(v, 8));
            const float mn = fmaxf(m[r], v);
            fac[r] = __expf(m[r] - mn);
            m[r] = mn;
        }
        f32x4 p[4];
#pragma unroll
        for (int c = 0; c < 4; c++)
#pragma unroll
            for (int r = 0; r < 4; r++)
                p[c][r] = __expf(s[c][r] - m[r]);
#pragma unroll
        for (int r = 0; r < 4; r++) {
            float rsv = p[0][r] + p[1][r] + p[2][r] + p[3][r];
            rsv += __shfl_xor(rsv, 1);
            rsv += __shfl_xor(rsv, 2);
            rsv += __shfl_xor(rsv, 4);
            rsv += __shfl_xor(rsv, 8);
            ls[r] = ls[r] * fac[r] + rsv;
        }
#pragma unroll
        for (int ct = 0; ct < 4; ct++)
#pragma unroll
            for (int r = 0; r < 4; r++) o[ct][r] *= fac[r];

        // P (D-layout) -> LDS row-major so it can be re-read as an A-fragment
#pragma unroll
        for (int c = 0; c < 4; c++)
#pragma unroll
            for (int r = 0; r < 4; r++)
                P_lds[w][(lane >> 4) * 4 + r][c * 16 + (lane & 15)] = f2bf(p[c][r]);

        bf16x8 pa0 = *(const bf16x8*)&P_lds[w][lane & 15][koff];
        bf16x8 pa1 = *(const bf16x8*)&P_lds[w][lane & 15][32 + koff];

        const short* vb = Vt + (size_t)b * 64 * 4096 + kt * 64;
#pragma unroll
        for (int ct = 0; ct < 4; ct++) {
            const short* vp = vb + (size_t)(ct * 16 + (lane & 15)) * 4096 + koff;
            bf16x8 vf0 = *(const bf16x8*)(vp);
            bf16x8 vf1 = *(const bf16x8*)(vp + 32);
            o[ct] = MFMA(pa0, vf0, o[ct]);
            o[ct] = MFMA(pa1, vf1, o[ct]);
        }
    }

    // publish per-wave partial state
    if ((lane & 15) == 0) {
#pragma unroll
        for (int r = 0; r < 4; r++) {
            c_m[w][(lane >> 4) * 4 + r] = m[r];
            c_l[w][(lane >> 4) * 4 + r] = ls[r];
        }
    }
#pragma unroll
    for (int ct = 0; ct < 4; ct++)
#pragma unroll
        for (int r = 0; r < 4; r++)
            c_o[w][(lane >> 4) * 4 + r][ct * 16 + (lane & 15)] = o[ct][r];
    __syncthreads();

    // merge the 4 wave-partials and write output
    for (int idx = threadIdx.x; idx < 16 * 64; idx += 256) {
        const int row = idx >> 6, col = idx & 63;
        const float M = fmaxf(fmaxf(c_m[0][row], c_m[1][row]),
                              fmaxf(c_m[2][row], c_m[3][row]));
        float L = 0.f, val = 0.f;
#pragma unroll
        for (int ww = 0; ww < 4; ww++) {
            const float e = __expf(c_m[ww][row] - M);
            L += e * c_l[ww][row];
            val += e * c_o[ww][row][col];
        }
        out[bbase + (size_t)(row16 + row) * 64 + col] = val / L;
    }
}

// ---------------------------------------------------------------------------
extern "C" void kernel_launch(void* const* d_in, const int* in_sizes, int n_in,
                              void* d_out, int out_size, void* d_ws, size_t ws_size,
                              hipStream_t stream) {
    const float* x  = (const float*)d_in[0];
    // d_in[1] = mask (causal tril) -- structure known, not read
    const float* Wk = (const float*)d_in[2];
    const float* bk = (const float*)d_in[3];
    const float* Wq = (const float*)d_in[4];
    const float* bq = (const float*)d_in[5];
    const float* Wv = (const float*)d_in[6];
    const float* bv = (const float*)d_in[7];
    float* out = (float*)d_out;

    char* ws = (char*)d_ws;
    short* WT    = (short*)(ws);                    // 192*1024*2 = 384 KB
    float* biasC = (float*)(ws + 393216);           // 768 B
    short* Qb    = (short*)(ws + (size_t)1 * (1 << 20));  // 2 MB (scaled by 0.125)
    short* Kb    = (short*)(ws + (size_t)3 * (1 << 20));  // 2 MB
    short* Vt    = (short*)(ws + (size_t)5 * (1 << 20));  // 2 MB, [b][hd][s]

    wt_prep<<<768, 256, 0, stream>>>(Wk, bk, Wq, bq, Wv, bv, WT, biasC);
    qkv_proj<<<256, 256, 0, stream>>>(x, WT, biasC, Qb, Kb, Vt);
    attn<<<1024, 256, 0, stream>>>(Qb, Kb, Vt, out);
}